// Round 13
// baseline (133.689 us; speedup 1.0000x reference)
//
#include <hip/hip_runtime.h>
#include <math.h>

// Problem constants
#define BATCH 64
#define SEQL  512
#define DIN   256
#define NF    256
#define KS    3
#define KF    (KS * NF)        // 768

// Fully fused, staging-free, fragment-packed weights + DEEP register
// pipeline (4-buffer rotation, 3 half-regions in flight):
//   One block = (b, 64-row slab), 256 threads (4 waves), 2 blocks/CU,
//   LDS = 4 panels [66][128] bf16 = 67.6 KB, TWO barriers total.
//   r12's 2-buffer ping-pong collapsed (VGPR 112): load target == compute
//   buffer (WAR) let the compiler sink loads. Fix: 4-buffer rotation,
//   load (h+3)%4 while computing h%4 -> always distinct, ~670 cyc in
//   flight vs ~300 cyc L2 latency. First G fragments preissued before
//   phase X; first conv halves preissued before the Y epilogue (T14).
//     WcTp[(g*3+k)][ks][f][16ch]  coalesced fragment stream (786 KB)
//     UTp [kk][e][quad][8d]       coalesced fragment stream (128 KB)
#define XCH 512
#define KC  (KS * XCH)          // 1536
#define PR2 66                  // 64 out rows + 2 halo
#define PLD 128                 // panel row stride in shorts (256 B)
#define P0SZ (PR2 * PLD)        // 8448 shorts per panel

typedef __attribute__((ext_vector_type(8))) short short8;
typedef __attribute__((ext_vector_type(4))) float floatx4;
typedef __attribute__((ext_vector_type(16))) float floatx16;
typedef __attribute__((ext_vector_type(8))) unsigned short ushort8v;
typedef __attribute__((ext_vector_type(4))) unsigned short ushort4v;

static __device__ __forceinline__ unsigned short f2bf(float f) {
    unsigned int u = __float_as_uint(f);
    return (unsigned short)((u + 0x7FFF + ((u >> 16) & 1)) >> 16);  // RTNE
}

// ---------------------------------------------------------------------------
// pack: fragment-pack weights (identical to rounds 11/12, verified).
// ---------------------------------------------------------------------------
__global__ __launch_bounds__(256) void pack_kernel(
    const float* __restrict__ U, const float* __restrict__ V,
    const float* __restrict__ Bw,
    unsigned short* __restrict__ WcTp, unsigned short* __restrict__ UTp)
{
    const int blk = blockIdx.x;
    const int t   = threadIdx.x;

    if (blk < 96) {
        const int gk = blk >> 3;            // 0..11 = g*3 + k
        const int g  = gk / 3, k = gk % 3;
        const int ks = t >> 5;              // 0..7
        const int f  = (blk & 7) * 32 + (t & 31);
        unsigned short* dst = WcTp + ((size_t)(gk * 8 + ks) * 256 + f) * 16;
        #pragma unroll
        for (int c = 0; c < 16; ++c) {
            const int ch = g * 128 + ks * 16 + c;
            const float v = (ch < DIN)
                ? Bw[(size_t)ch * KF + k * NF + f]
                : V[(size_t)(ch - DIN) * KF + k * NF + f];
            dst[c] = f2bf(v);
        }
    } else {
        const int bb = blk - 96;            // 0..15
        const int kk = bb >> 1;             // 0..7
        const int e0 = (bb & 1) * 128;
        #pragma unroll
        for (int it = 0; it < 2; ++it) {
            const int p    = t + it * 256;  // 0..511
            const int e    = e0 + (p >> 2);
            const int quad = p & 3;
            unsigned short* dst =
                UTp + ((size_t)(kk * 256 + e) * 4 + quad) * 8;
            #pragma unroll
            for (int c = 0; c < 8; ++c) {
                const int d = kk * 32 + quad * 8 + c;
                dst[c] = f2bf(U[(size_t)d * DIN + e]);
            }
        }
    }
}

// ---------------------------------------------------------------------------
// fused kernel. Grid 512 x 256. LDS 67584 B -> 2 blocks/CU.
// ---------------------------------------------------------------------------
__global__ __launch_bounds__(256, 2) void fused_kernel(
    const float* __restrict__ x, const float* __restrict__ z,
    const unsigned short* __restrict__ UTp,
    const unsigned short* __restrict__ WcTp,
    const float* __restrict__ bias, float* __restrict__ out)
{
    __shared__ __align__(16) unsigned short lds[4 * P0SZ];   // 67584 B

    const int tid  = threadIdx.x;
    const int lane = tid & 63;
    const int wave = tid >> 6;               // 0..3
    const int quad = lane >> 4, l16 = lane & 15;
    const int l32  = lane & 31, hi  = lane >> 5;

    const int bid = blockIdx.x;
    const int b   = bid >> 3;
    const int l0  = (bid & 7) * 64;

    // ---- G-stream fragment buffers (UTp, coalesced), 4-deep rotation ------
    short8 uf[4][4];
    auto loadU = [&](int kk, int s) {
        #pragma unroll
        for (int q = 0; q < 4; ++q) {
            const int e = q * 64 + wave * 16 + l16;
            uf[s][q] = *(const short8*)
                &UTp[((size_t)(kk * 256 + e) * 4 + quad) * 8];
        }
    };

    // preissue G chunks 0..2: latency hides under phase X
    loadU(0, 0); loadU(1, 1); loadU(2, 2);

    // ---------------- phase X: x -> P0, P1 (bf16, swizzled) ----------------
    #pragma unroll
    for (int p = 0; p < 2; ++p) {
        unsigned short* P = lds + (size_t)p * P0SZ;
        #pragma unroll
        for (int it = 0; it < 5; ++it) {
            const int idx = tid + it * 256;
            if (idx < PR2 * 16) {
                const int row = idx >> 4, u = idx & 15;
                const int l = l0 - 1 + row;
                ushort8v h = {};
                if (l >= 0 && l < SEQL) {
                    const float* xp =
                        x + ((size_t)b * SEQL + l) * DIN + p * 128 + u * 8;
                    const float4 v0 = *(const float4*)xp;
                    const float4 v1 = *(const float4*)(xp + 4);
                    h[0] = f2bf(v0.x); h[1] = f2bf(v0.y);
                    h[2] = f2bf(v0.z); h[3] = f2bf(v0.w);
                    h[4] = f2bf(v1.x); h[5] = f2bf(v1.y);
                    h[6] = f2bf(v1.z); h[7] = f2bf(v1.w);
                }
                *(ushort8v*)&P[row * PLD + ((u ^ (row & 15)) << 3)] = h;
            }
        }
    }
    __syncthreads();                              // barrier 1 of 2

    // ---------------- phase G: Y = (x@U)*sigmoid(z), operand-swapped -------
    // accY = mfma(A = UTp fragment (4-deep reg pipeline), B = x from LDS).
    // D[e][xrow]: lane holds e = q*64+wave*16+quad*4+reg, xrow = i*16+l16.
    floatx4 accY[4][5] = {};
    {
        #pragma unroll
        for (int kk = 0; kk < 8; ++kk) {
            if (kk + 3 < 8) loadU(kk + 3, (kk + 3) & 3);   // 3 ahead
            const unsigned short* P = lds + (size_t)(kk >> 2) * P0SZ;
            const int ux = (kk & 3) * 4 + quad;
            const int s  = kk & 3;
            __builtin_amdgcn_s_setprio(1);
            #pragma unroll
            for (int i = 0; i < 5; ++i) {
                const int row = i * 16 + l16; // rows>=66 garbage, masked later
                const short8 xf = *(const short8*)
                    &P[row * PLD + ((ux ^ (row & 15)) << 3)];
                #pragma unroll
                for (int q = 0; q < 4; ++q)
                    accY[q][i] = __builtin_amdgcn_mfma_f32_16x16x32_bf16(
                        uf[s][q], xf, accY[q][i], 0, 0, 0);
            }
            __builtin_amdgcn_s_setprio(0);
        }
    }

    // ---- conv-stream fragment buffers (WcTp, coalesced), 4-deep rotation --
    // half-region h (0..23): r = h>>1 -> (g,k); ks0 = (h&1)*4.
    short8 cb[4][8];
    auto loadH = [&](int h, int s) {
        const int r  = h >> 1;
        const int gg = r / 3, k = r - gg * 3;
        const int g  = (gg + (bid & 3)) & 3;
        const unsigned short* gW = WcTp + (size_t)(g * 3 + k) * 8 * 4096;
        const int ks0 = (h & 1) * 4;
        #pragma unroll
        for (int ks2 = 0; ks2 < 4; ++ks2)
            #pragma unroll
            for (int j = 0; j < 2; ++j) {
                const int f = wave * 64 + j * 32 + l32;
                cb[s][ks2 * 2 + j] = *(const short8*)
                    &gW[(size_t)(ks0 + ks2) * 4096 + (size_t)f * 16 + hi * 8];
            }
    };

    // preissue conv halves 0..2: latency hides under Y-epilogue + barrier
    loadH(0, 0); loadH(1, 1); loadH(2, 2);

    // Y epilogue: lane holds 4 consecutive e -> b64 writes into P2/P3.
    #pragma unroll
    for (int q = 0; q < 4; ++q) {
        const int e0 = q * 64 + wave * 16 + quad * 4;    // 0..252
        unsigned short* PY = lds + (size_t)(2 + (q >> 1)) * P0SZ;
        const int c0 = e0 & 127;
        float zf[4];
        #pragma unroll
        for (int r2 = 0; r2 < 4; ++r2)
            zf[r2] = 1.0f / (1.0f + expf(-z[(size_t)b * DIN + e0 + r2]));
        const int u = c0 >> 3;
        #pragma unroll
        for (int i = 0; i < 5; ++i) {
            const int xrow = i * 16 + l16;
            if (xrow < PR2) {
                ushort4v h;
                #pragma unroll
                for (int r2 = 0; r2 < 4; ++r2)
                    h[r2] = f2bf(accY[q][i][r2] * zf[r2]);
                *(ushort4v*)&PY[xrow * PLD + ((u ^ (xrow & 15)) << 3) +
                                (c0 & 7)] = h;
            }
        }
    }
    __syncthreads();                              // barrier 2 of 2

    // ---------------- conv: 24 half-regions, 3-ahead pipeline --------------
    floatx16 acc2[2][2] = {};
    {
        #pragma unroll
        for (int h = 0; h < 24; ++h) {
            if (h + 3 < 24) loadH(h + 3, (h + 3) & 3);     // 3 ahead
            const int r  = h >> 1;
            const int gg = r / 3, k = r - gg * 3;
            const int g  = (gg + (bid & 3)) & 3;
            const unsigned short* P = lds + (size_t)g * P0SZ;
            const int ks0 = (h & 1) * 4;
            const int s   = h & 3;
            __builtin_amdgcn_s_setprio(1);
            #pragma unroll
            for (int ks2 = 0; ks2 < 4; ++ks2) {
                const int ks = ks0 + ks2;
                short8 af[2];
                const int ua = ks * 2 + hi;
                #pragma unroll
                for (int i = 0; i < 2; ++i) {
                    const int m = i * 32 + l32 + k;          // 0..65
                    af[i] = *(const short8*)
                        &P[m * PLD + ((ua ^ (m & 15)) << 3)];
                }
                #pragma unroll
                for (int i = 0; i < 2; ++i)
                    #pragma unroll
                    for (int j = 0; j < 2; ++j)
                        acc2[i][j] = __builtin_amdgcn_mfma_f32_32x32x16_bf16(
                            af[i], cb[s][ks2 * 2 + j], acc2[i][j], 0, 0, 0);
            }
            __builtin_amdgcn_s_setprio(0);
        }
    }

    // ---------------- epilogue: bias + relu -> out -------------------------
    #pragma unroll
    for (int j = 0; j < 2; ++j) {
        const int f  = wave * 64 + j * 32 + l32;
        const float bv = bias[f];
        #pragma unroll
        for (int i = 0; i < 2; ++i) {
            #pragma unroll
            for (int reg = 0; reg < 16; ++reg) {
                const int rowl = i * 32 + (reg & 3) + 8 * (reg >> 2) + 4 * hi;
                const float v = acc2[i][j][reg] + bv;
                out[((size_t)b * SEQL + l0 + rowl) * NF + f] = fmaxf(v, 0.0f);
            }
        }
    }
}

extern "C" void kernel_launch(void* const* d_in, const int* in_sizes, int n_in,
                              void* d_out, int out_size, void* d_ws, size_t ws_size,
                              hipStream_t stream) {
    const float* x    = (const float*)d_in[0];
    const float* z    = (const float*)d_in[1];
    const float* U    = (const float*)d_in[2];
    const float* V    = (const float*)d_in[3];
    const float* Bw   = (const float*)d_in[4];
    const float* bias = (const float*)d_in[5];

    unsigned short* WcTp = (unsigned short*)d_ws;            // 393216 shorts
    unsigned short* UTp  = WcTp + (size_t)12 * 8 * 256 * 16; // 65536 shorts
    float* out = (float*)d_out;

    pack_kernel<<<dim3(112), 256, 0, stream>>>(U, V, Bw, WcTp, UTp);
    fused_kernel<<<dim3(512), 256, 0, stream>>>(x, z, UTp, WcTp, bias, out);
}

// Round 14
// 126.208 us; speedup vs baseline: 1.0593x; 1.0593x over previous
//
#include <hip/hip_runtime.h>
#include <math.h>

// Problem constants
#define BATCH 64
#define SEQL  512
#define DIN   256
#define NF    256
#define KS    3
#define KF    (KS * NF)        // 768

// Fully fused, staging-free, fragment-packed weights, HIGH-OCCUPANCY:
//   512-thread blocks (8 waves), 64-row slab, grid 512 -> 2 blocks/CU,
//   16 waves/CU = 4 waves/SIMD (was 2). Per-wave tiles halved so VGPR
//   fits the 128 cap at 4 waves/SIMD:
//     G:    accY[2][5] (40 VGPR), e = q*128 + wave*16 + l16
//     conv: acc2[2]    (32 VGPR), wave tile 64 rows x 32 f
//   Weight streams identical to r12 (each f read once per block):
//     WcTp[(g*3+k)][ks][f][16ch]  coalesced fragment stream (786 KB)
//     UTp [kk][e][quad][8d]       coalesced fragment stream (128 KB)
//   LDS = 4 panels [66][128] bf16 = 67.6 KB, TWO barriers total.
#define XCH 512
#define KC  (KS * XCH)          // 1536
#define PR2 66                  // 64 out rows + 2 halo
#define PLD 128                 // panel row stride in shorts (256 B)
#define P0SZ (PR2 * PLD)        // 8448 shorts per panel

typedef __attribute__((ext_vector_type(8))) short short8;
typedef __attribute__((ext_vector_type(4))) float floatx4;
typedef __attribute__((ext_vector_type(16))) float floatx16;
typedef __attribute__((ext_vector_type(8))) unsigned short ushort8v;
typedef __attribute__((ext_vector_type(4))) unsigned short ushort4v;

static __device__ __forceinline__ unsigned short f2bf(float f) {
    unsigned int u = __float_as_uint(f);
    return (unsigned short)((u + 0x7FFF + ((u >> 16) & 1)) >> 16);  // RTNE
}

// ---------------------------------------------------------------------------
// pack: fragment-pack weights (identical to rounds 11/12, verified).
// ---------------------------------------------------------------------------
__global__ __launch_bounds__(256) void pack_kernel(
    const float* __restrict__ U, const float* __restrict__ V,
    const float* __restrict__ Bw,
    unsigned short* __restrict__ WcTp, unsigned short* __restrict__ UTp)
{
    const int blk = blockIdx.x;
    const int t   = threadIdx.x;

    if (blk < 96) {
        const int gk = blk >> 3;            // 0..11 = g*3 + k
        const int g  = gk / 3, k = gk % 3;
        const int ks = t >> 5;              // 0..7
        const int f  = (blk & 7) * 32 + (t & 31);
        unsigned short* dst = WcTp + ((size_t)(gk * 8 + ks) * 256 + f) * 16;
        #pragma unroll
        for (int c = 0; c < 16; ++c) {
            const int ch = g * 128 + ks * 16 + c;
            const float v = (ch < DIN)
                ? Bw[(size_t)ch * KF + k * NF + f]
                : V[(size_t)(ch - DIN) * KF + k * NF + f];
            dst[c] = f2bf(v);
        }
    } else {
        const int bb = blk - 96;            // 0..15
        const int kk = bb >> 1;             // 0..7
        const int e0 = (bb & 1) * 128;
        #pragma unroll
        for (int it = 0; it < 2; ++it) {
            const int p    = t + it * 256;  // 0..511
            const int e    = e0 + (p >> 2);
            const int quad = p & 3;
            unsigned short* dst =
                UTp + ((size_t)(kk * 256 + e) * 4 + quad) * 8;
            #pragma unroll
            for (int c = 0; c < 8; ++c) {
                const int d = kk * 32 + quad * 8 + c;
                dst[c] = f2bf(U[(size_t)d * DIN + e]);
            }
        }
    }
}

// ---------------------------------------------------------------------------
// fused kernel. Grid 512 x 512. LDS 67584 B -> 2 blocks/CU, 4 waves/SIMD.
// ---------------------------------------------------------------------------
__global__ __launch_bounds__(512, 4) void fused_kernel(
    const float* __restrict__ x, const float* __restrict__ z,
    const unsigned short* __restrict__ UTp,
    const unsigned short* __restrict__ WcTp,
    const float* __restrict__ bias, float* __restrict__ out)
{
    __shared__ __align__(16) unsigned short lds[4 * P0SZ];   // 67584 B

    const int tid  = threadIdx.x;
    const int lane = tid & 63;
    const int wave = tid >> 6;               // 0..7
    const int quad = lane >> 4, l16 = lane & 15;
    const int l32  = lane & 31, hi  = lane >> 5;

    const int bid = blockIdx.x;
    const int b   = bid >> 3;
    const int l0  = (bid & 7) * 64;

    // ---- G-stream fragment buffers (UTp, coalesced), ping-pong ------------
    short8 uA[2], uB[2];
    auto loadU = [&](int kk, short8 (&buf)[2]) {
        #pragma unroll
        for (int q = 0; q < 2; ++q) {
            const int e = q * 128 + wave * 16 + l16;
            buf[q] = *(const short8*)
                &UTp[((size_t)(kk * 256 + e) * 4 + quad) * 8];
        }
    };

    // issue first G fragments immediately: latency hides under phase X
    loadU(0, uA);

    // ---------------- phase X: x -> P0, P1 (bf16, swizzled) ----------------
    #pragma unroll
    for (int p = 0; p < 2; ++p) {
        unsigned short* P = lds + (size_t)p * P0SZ;
        #pragma unroll
        for (int it = 0; it < 3; ++it) {
            const int idx = tid + it * 512;
            if (idx < PR2 * 16) {
                const int row = idx >> 4, u = idx & 15;
                const int l = l0 - 1 + row;
                ushort8v h = {};
                if (l >= 0 && l < SEQL) {
                    const float* xp =
                        x + ((size_t)b * SEQL + l) * DIN + p * 128 + u * 8;
                    const float4 v0 = *(const float4*)xp;
                    const float4 v1 = *(const float4*)(xp + 4);
                    h[0] = f2bf(v0.x); h[1] = f2bf(v0.y);
                    h[2] = f2bf(v0.z); h[3] = f2bf(v0.w);
                    h[4] = f2bf(v1.x); h[5] = f2bf(v1.y);
                    h[6] = f2bf(v1.z); h[7] = f2bf(v1.w);
                }
                *(ushort8v*)&P[row * PLD + ((u ^ (row & 15)) << 3)] = h;
            }
        }
    }
    __syncthreads();                              // barrier 1 of 2

    // ---------------- phase G: Y = (x@U)*sigmoid(z), operand-swapped -------
    // accY = mfma(A = UTp fragment (reg ping-pong), B = x from LDS).
    // D[e][xrow]: lane holds e = q*128+wave*16+quad*4+reg, xrow = i*16+l16.
    floatx4 accY[2][5] = {};
    {
        auto computeG = [&](int kk, const short8 (&buf)[2]) {
            const unsigned short* P = lds + (size_t)(kk >> 2) * P0SZ;
            const int ux = (kk & 3) * 4 + quad;
            __builtin_amdgcn_s_setprio(1);
            #pragma unroll
            for (int i = 0; i < 5; ++i) {
                const int row = i * 16 + l16; // rows>=66 garbage, masked later
                const short8 xf = *(const short8*)
                    &P[row * PLD + ((ux ^ (row & 15)) << 3)];
                #pragma unroll
                for (int q = 0; q < 2; ++q)
                    accY[q][i] = __builtin_amdgcn_mfma_f32_16x16x32_bf16(
                        buf[q], xf, accY[q][i], 0, 0, 0);
            }
            __builtin_amdgcn_s_setprio(0);
        };
        #pragma unroll 1
        for (int kb = 0; kb < 4; ++kb) {
            const int kk = kb * 2;
            loadU(kk + 1, uB);
            computeG(kk, uA);
            if (kk + 2 < 8) loadU(kk + 2, uA);
            computeG(kk + 1, uB);
        }
    }

    // ---- conv-stream fragment buffers (WcTp, coalesced), ping-pong --------
    // half-region h (0..23): r = h>>1 -> (g,k); ks0 = (h&1)*4. 4 frags.
    short8 cA[4], cB[4];
    auto loadH = [&](int h, short8 (&buf)[4]) {
        const int r  = h >> 1;
        const int gg = r / 3, k = r - gg * 3;
        const int g  = (gg + (bid & 3)) & 3;
        const unsigned short* gW = WcTp + (size_t)(g * 3 + k) * 8 * 4096;
        const int ks0 = (h & 1) * 4;
        const int f   = wave * 32 + l32;
        #pragma unroll
        for (int ks2 = 0; ks2 < 4; ++ks2)
            buf[ks2] = *(const short8*)
                &gW[(size_t)(ks0 + ks2) * 4096 + (size_t)f * 16 + hi * 8];
    };

    // issue first conv half now: latency hides under Y-epilogue + barrier
    loadH(0, cA);

    // Y epilogue: lane holds 4 consecutive e -> b64 writes into P2/P3.
    #pragma unroll
    for (int q = 0; q < 2; ++q) {
        const int e0 = q * 128 + wave * 16 + quad * 4;   // 0..252
        unsigned short* PY = lds + (size_t)(2 + q) * P0SZ;
        const int c0 = e0 & 127;                          // = wave*16+quad*4
        float zf[4];
        #pragma unroll
        for (int r2 = 0; r2 < 4; ++r2)
            zf[r2] = 1.0f / (1.0f + expf(-z[(size_t)b * DIN + e0 + r2]));
        const int u = c0 >> 3;
        #pragma unroll
        for (int i = 0; i < 5; ++i) {
            const int xrow = i * 16 + l16;
            if (xrow < PR2) {
                ushort4v h;
                #pragma unroll
                for (int r2 = 0; r2 < 4; ++r2)
                    h[r2] = f2bf(accY[q][i][r2] * zf[r2]);
                *(ushort4v*)&PY[xrow * PLD + ((u ^ (xrow & 15)) << 3) +
                                (c0 & 7)] = h;
            }
        }
    }
    __syncthreads();                              // barrier 2 of 2

    // ---------------- conv: 24 half-regions, ping-pong, barrier-free -------
    // Per wave: 64 rows x 32 f (f = wave*32 + l32).
    floatx16 acc2[2] = {};
    {
        auto computeH = [&](int h, const short8 (&buf)[4]) {
            const int r  = h >> 1;
            const int gg = r / 3, k = r - gg * 3;
            const int g  = (gg + (bid & 3)) & 3;
            const unsigned short* P = lds + (size_t)g * P0SZ;
            const int ks0 = (h & 1) * 4;
            __builtin_amdgcn_s_setprio(1);
            #pragma unroll
            for (int ks2 = 0; ks2 < 4; ++ks2) {
                const int ks = ks0 + ks2;
                short8 af[2];
                const int ua = ks * 2 + hi;
                #pragma unroll
                for (int i = 0; i < 2; ++i) {
                    const int m = i * 32 + l32 + k;          // 0..65
                    af[i] = *(const short8*)
                        &P[m * PLD + ((ua ^ (m & 15)) << 3)];
                }
                #pragma unroll
                for (int i = 0; i < 2; ++i)
                    acc2[i] = __builtin_amdgcn_mfma_f32_32x32x16_bf16(
                        af[i], buf[ks2], acc2[i], 0, 0, 0);
            }
            __builtin_amdgcn_s_setprio(0);
        };
        #pragma unroll 1
        for (int hh = 0; hh < 12; ++hh) {
            const int h = hh * 2;
            loadH(h + 1, cB);
            computeH(h, cA);
            if (h + 2 < 24) loadH(h + 2, cA);
            computeH(h + 1, cB);
        }
    }

    // ---------------- epilogue: bias + relu -> out -------------------------
    {
        const int f  = wave * 32 + l32;
        const float bv = bias[f];
        #pragma unroll
        for (int i = 0; i < 2; ++i) {
            #pragma unroll
            for (int reg = 0; reg < 16; ++reg) {
                const int rowl = i * 32 + (reg & 3) + 8 * (reg >> 2) + 4 * hi;
                const float v = acc2[i][reg] + bv;
                out[((size_t)b * SEQL + l0 + rowl) * NF + f] = fmaxf(v, 0.0f);
            }
        }
    }
}

extern "C" void kernel_launch(void* const* d_in, const int* in_sizes, int n_in,
                              void* d_out, int out_size, void* d_ws, size_t ws_size,
                              hipStream_t stream) {
    const float* x    = (const float*)d_in[0];
    const float* z    = (const float*)d_in[1];
    const float* U    = (const float*)d_in[2];
    const float* V    = (const float*)d_in[3];
    const float* Bw   = (const float*)d_in[4];
    const float* bias = (const float*)d_in[5];

    unsigned short* WcTp = (unsigned short*)d_ws;            // 393216 shorts
    unsigned short* UTp  = WcTp + (size_t)12 * 8 * 256 * 16; // 65536 shorts
    float* out = (float*)d_out;

    pack_kernel<<<dim3(112), 256, 0, stream>>>(U, V, Bw, WcTp, UTp);
    fused_kernel<<<dim3(512), 512, 0, stream>>>(x, z, UTp, WcTp, bias, out);
}